// Round 6
// baseline (422.965 us; speedup 1.0000x reference)
//
#include <hip/hip_runtime.h>
#include <hip/hip_cooperative_groups.h>

namespace cg = cooperative_groups;

#define N_NODES 100000
#define N_EDGES 1600000
#define VOCAB   1000
#define EMB_DIM 64
#define OUT_DIM 32

#define BKT_BITS 9
#define BKT_SIZE 512
#define NBKT ((N_NODES + BKT_SIZE - 1) / BKT_SIZE)     // 196
#define CAP  12288                                     // per-bucket record capacity
#define GRID 512
#define TPB  512
#define CHUNK (N_EDGES / GRID)                         // 3125 exact
#define SPLIT 2
#define NPART (NBKT * SPLIT)                           // 392

__device__ __forceinline__ void fatomic_add(float* p, float v) {
    unsafeAtomicAdd(p, v);   // ds_add_f32 / global_atomic_add_f32
}

// ===========================================================================
// Fused cooperative kernel: all phases, grid.sync between them.
// record: x = (row<<9) | local_col, y = w_bits ; keyed by col>>9
// ===========================================================================
__global__ void __launch_bounds__(TPB, 4) k_fused(
        const int* __restrict__ node_seq, const int* __restrict__ row,
        const int* __restrict__ col, const float* __restrict__ ew,
        const float* __restrict__ emb, const float* __restrict__ W,
        const float* __restrict__ bias, float* __restrict__ out,
        int* __restrict__ cursors, uint2* __restrict__ recs,
        uint2* __restrict__ disseq, float* __restrict__ gcoeff,
        float* __restrict__ coeff)
{
    cg::grid_group grid = cg::this_grid();
    __shared__ uint2 stage[CHUNK];                 // 25.0 KB
    __shared__ unsigned char seg[CHUNK];           //  3.1 KB
    __shared__ int cnt[NBKT], lofs[NBKT], gbase[NBKT];
    __shared__ int sc[TPB];
    __shared__ float acc[BKT_SIZE];                // deg acc / dloc
    __shared__ float lc[VOCAB];
    __shared__ float tk[8 * 64];

    const int tid = threadIdx.x;
    const int bid = blockIdx.x;

    // ---- phase 0: init cursors ----
    {
        int g = bid * TPB + tid;
        if (g < NBKT) cursors[g] = g * CAP;
    }
    grid.sync();

    // ---- phase 1: LDS counting-sort scatter, coalesced segment writes ----
    {
        const int e0 = bid * CHUNK;
        for (int i = tid; i < NBKT; i += TPB) cnt[i] = 0;
        __syncthreads();
        for (int i = tid; i < CHUNK; i += TPB)
            atomicAdd(&cnt[col[e0 + i] >> BKT_BITS], 1);
        __syncthreads();
        sc[tid] = (tid < NBKT) ? cnt[tid] : 0;
        __syncthreads();
        for (int d = 1; d < TPB; d <<= 1) {
            int v = (tid >= d) ? sc[tid - d] : 0;
            __syncthreads();
            sc[tid] += v;
            __syncthreads();
        }
        if (tid < NBKT) {
            lofs[tid]  = sc[tid] - cnt[tid];
            gbase[tid] = atomicAdd(&cursors[tid], cnt[tid]);
            cnt[tid]   = 0;
        }
        __syncthreads();
        for (int i = tid; i < CHUNK; i += TPB) {
            int c = col[e0 + i];                    // L2-warm second read
            int r = row[e0 + i];
            int b = c >> BKT_BITS;
            int p = lofs[b] + atomicAdd(&cnt[b], 1);
            stage[p] = make_uint2(((unsigned)r << BKT_BITS) | (unsigned)(c & (BKT_SIZE - 1)),
                                  __float_as_uint(ew[e0 + i]));
            seg[p] = (unsigned char)b;
        }
        __syncthreads();
        for (int i = tid; i < CHUNK; i += TPB) {
            int b = seg[i];
            recs[gbase[b] + (i - lofs[b])] = stage[i];
        }
    }
    grid.sync();

    // ---- phase 2: per-bucket degree -> disseq = {rsqrt(1+deg), seq} ----
    if (bid < NBKT) {
        const int b = bid;
        for (int i = tid; i < BKT_SIZE; i += TPB) acc[i] = 0.0f;
        __syncthreads();
        const int base = b * CAP;
        const int c2 = cursors[b] - base;
        for (int i = tid; i < c2; i += TPB) {
            uint2 rr = recs[base + i];
            fatomic_add(&acc[rr.x & (BKT_SIZE - 1)], __uint_as_float(rr.y));
        }
        __syncthreads();
        const int n0 = b << BKT_BITS;
        for (int i = tid; i < BKT_SIZE; i += TPB) {
            int n = n0 + i;
            if (n < N_NODES)
                disseq[n] = make_uint2(__float_as_uint(__frsqrt_rn(1.0f + acc[i])),
                                       (unsigned)node_seq[n]);
        }
    }
    grid.sync();

    // ---- phase 3: per-(bucket,half) vocab histogram; 1 8B gather/edge ----
    if (bid < NPART) {
        const int b = bid >> 1, half = bid & 1;
        const int n0 = b << BKT_BITS;
        for (int i = tid; i < VOCAB; i += TPB) lc[i] = 0.0f;
        if (tid < BKT_SIZE) {
            int n = n0 + tid;
            acc[tid] = (n < N_NODES) ? __uint_as_float(disseq[n].x) : 0.0f;
        }
        __syncthreads();
        const int base = b * CAP;
        const int c3 = cursors[b] - base;
        const int lo = half ? (c3 + 1) / 2 : 0;
        const int hi = half ? c3 : (c3 + 1) / 2;
        for (int i = lo + tid; i < hi; i += TPB) {
            uint2 rec = recs[base + i];
            int lcol = rec.x & (BKT_SIZE - 1);
            int r    = rec.x >> BKT_BITS;
            uint2 ds = disseq[r];                   // single 8B L2 gather
            fatomic_add(&lc[ds.y],
                __uint_as_float(ds.x) * __uint_as_float(rec.y) * acc[lcol]);
        }
        if (half == 0 && tid < BKT_SIZE) {          // self loops
            int n = n0 + tid;
            if (n < N_NODES) {
                uint2 ds = disseq[n];
                float d = __uint_as_float(ds.x);
                fatomic_add(&lc[ds.y], d * d);
            }
        }
        __syncthreads();
        for (int i = tid; i < VOCAB; i += TPB)
            gcoeff[bid * VOCAB + i] = lc[i];
    }
    grid.sync();

    // ---- phase 4: reduce partials, one wave per vocab slot ----
    {
        int gw = (bid * TPB + tid) >> 6;
        int l  = tid & 63;
        if (gw < VOCAB) {
            float s = 0.0f;
            for (int p = l; p < NPART; p += 64) s += gcoeff[p * VOCAB + gw];
            for (int off = 32; off > 0; off >>= 1) s += __shfl_down(s, off, 64);
            if (l == 0) coeff[gw] = s;
        }
    }
    grid.sync();

    // ---- phase 5: out[d] = (sum_v coeff[v]*(emb@W)[v,d])/N + b[d] ----
    if (bid == 0) {
        for (int v = tid; v < VOCAB; v += TPB) lc[v] = coeff[v];
        __syncthreads();
        int k = tid & 63;
        int g = tid >> 6;                           // 0..7
        float p = 0.0f;
        for (int v = g; v < VOCAB; v += 8) p += lc[v] * emb[v * EMB_DIM + k];
        tk[g * 64 + k] = p;
        __syncthreads();
        if (tid < 64) {
            float s = 0.0f;
            for (int gg = 0; gg < 8; ++gg) s += tk[gg * 64 + tid];
            tk[tid] = s;
        }
        __syncthreads();
        if (tid < OUT_DIM) {
            float s = 0.0f;
            for (int kk = 0; kk < EMB_DIM; ++kk) s += tk[kk] * W[kk * OUT_DIM + tid];
            out[tid] = s * (1.0f / (float)N_NODES) + bias[tid];
        }
    }
}

// ===========================================================================
// Fallback: proven r4 multi-kernel path (used only if coop launch errors)
// ===========================================================================
__global__ void k_init(int* __restrict__ cursors) {
    int i = blockIdx.x * blockDim.x + threadIdx.x;
    if (i < NBKT) cursors[i] = i * CAP;
}

#define NSB  512
#define FCHUNK (N_EDGES / NSB)   // 3125

__global__ void __launch_bounds__(256) k_scatter(
        const int* __restrict__ row, const int* __restrict__ col,
        const float* __restrict__ w, int* __restrict__ cursors,
        uint2* __restrict__ recs) {
    __shared__ uint2 stage[FCHUNK];
    __shared__ unsigned char seg[FCHUNK];
    __shared__ int cnt[NBKT], lofs[NBKT], gbase[NBKT];
    __shared__ int sc[256];
    const int tid = threadIdx.x;
    const int e0 = blockIdx.x * FCHUNK;
    for (int i = tid; i < NBKT; i += 256) cnt[i] = 0;
    __syncthreads();
    for (int i = tid; i < FCHUNK; i += 256)
        atomicAdd(&cnt[col[e0 + i] >> BKT_BITS], 1);
    __syncthreads();
    sc[tid] = (tid < NBKT) ? cnt[tid] : 0;
    __syncthreads();
    for (int d = 1; d < 256; d <<= 1) {
        int v = (tid >= d) ? sc[tid - d] : 0;
        __syncthreads();
        sc[tid] += v;
        __syncthreads();
    }
    if (tid < NBKT) {
        lofs[tid]  = sc[tid] - cnt[tid];
        gbase[tid] = atomicAdd(&cursors[tid], cnt[tid]);
        cnt[tid]   = 0;
    }
    __syncthreads();
    for (int i = tid; i < FCHUNK; i += 256) {
        int c = col[e0 + i];
        int r = row[e0 + i];
        int b = c >> BKT_BITS;
        int p = lofs[b] + atomicAdd(&cnt[b], 1);
        stage[p] = make_uint2(((unsigned)r << BKT_BITS) | (unsigned)(c & (BKT_SIZE - 1)),
                              __float_as_uint(w[e0 + i]));
        seg[p] = (unsigned char)b;
    }
    __syncthreads();
    for (int i = tid; i < FCHUNK; i += 256) {
        int b = seg[i];
        recs[gbase[b] + (i - lofs[b])] = stage[i];
    }
}

__global__ void __launch_bounds__(256) k_dis(
        const uint2* __restrict__ recs, const int* __restrict__ cursors,
        const int* __restrict__ node_seq, uint2* __restrict__ disseq) {
    __shared__ float acc[BKT_SIZE];
    const int b = blockIdx.x;
    for (int i = threadIdx.x; i < BKT_SIZE; i += 256) acc[i] = 0.0f;
    __syncthreads();
    const int base = b * CAP;
    const int cnt = cursors[b] - base;
    for (int i = threadIdx.x; i < cnt; i += 256) {
        uint2 r = recs[base + i];
        fatomic_add(&acc[r.x & (BKT_SIZE - 1)], __uint_as_float(r.y));
    }
    __syncthreads();
    const int n0 = b << BKT_BITS;
    for (int i = threadIdx.x; i < BKT_SIZE && n0 + i < N_NODES; i += 256)
        disseq[n0 + i] = make_uint2(__float_as_uint(__frsqrt_rn(1.0f + acc[i])),
                                    (unsigned)node_seq[n0 + i]);
}

__global__ void __launch_bounds__(512) k_coeff(
        const uint2* __restrict__ recs, const int* __restrict__ cursors,
        const uint2* __restrict__ disseq, float* __restrict__ gcoeff) {
    __shared__ float dloc[BKT_SIZE];
    __shared__ float lc[VOCAB];
    const int b = blockIdx.x;
    const int n0 = b << BKT_BITS;
    for (int i = threadIdx.x; i < VOCAB; i += 512) lc[i] = 0.0f;
    if (threadIdx.x < BKT_SIZE) {
        int n = n0 + threadIdx.x;
        dloc[threadIdx.x] = (n < N_NODES) ? __uint_as_float(disseq[n].x) : 0.0f;
    }
    __syncthreads();
    const int base = b * CAP;
    const int cnt = cursors[b] - base;
    for (int i = threadIdx.x; i < cnt; i += 512) {
        uint2 rec = recs[base + i];
        int lcol = rec.x & (BKT_SIZE - 1);
        int r    = rec.x >> BKT_BITS;
        uint2 ds = disseq[r];
        fatomic_add(&lc[ds.y],
            __uint_as_float(ds.x) * __uint_as_float(rec.y) * dloc[lcol]);
    }
    if (threadIdx.x < BKT_SIZE) {
        int n = n0 + threadIdx.x;
        if (n < N_NODES) {
            uint2 ds = disseq[n];
            float d = __uint_as_float(ds.x);
            fatomic_add(&lc[ds.y], d * d);
        }
    }
    __syncthreads();
    for (int i = threadIdx.x; i < VOCAB; i += 512)
        gcoeff[b * VOCAB + i] = lc[i];
}

__global__ void __launch_bounds__(256) k_reduce(
        const float* __restrict__ gcoeff, float* __restrict__ coeff, int npart) {
    int g = blockIdx.x * 256 + threadIdx.x;
    int v = g >> 6;
    int l = g & 63;
    if (v >= VOCAB) return;
    float s = 0.0f;
    for (int p = l; p < npart; p += 64) s += gcoeff[p * VOCAB + v];
    for (int off = 32; off > 0; off >>= 1) s += __shfl_down(s, off, 64);
    if (l == 0) coeff[v] = s;
}

__global__ void __launch_bounds__(1024) k_final(
        const float* __restrict__ coeff, const float* __restrict__ emb,
        const float* __restrict__ W, const float* __restrict__ bias,
        float* __restrict__ out) {
    __shared__ float lc[VOCAB];
    __shared__ float tk[16 * 64];
    int t = threadIdx.x;
    for (int v = t; v < VOCAB; v += 1024) lc[v] = coeff[v];
    __syncthreads();
    int k = t & 63;
    int g = t >> 6;
    float p = 0.0f;
    for (int v = g; v < VOCAB; v += 16) p += lc[v] * emb[v * EMB_DIM + k];
    tk[g * 64 + k] = p;
    __syncthreads();
    if (t < 64) {
        float s = 0.0f;
        for (int gg = 0; gg < 16; ++gg) s += tk[gg * 64 + t];
        tk[t] = s;
    }
    __syncthreads();
    if (t < OUT_DIM) {
        float s = 0.0f;
        for (int kk = 0; kk < EMB_DIM; ++kk) s += tk[kk] * W[kk * OUT_DIM + t];
        out[t] = s * (1.0f / (float)N_NODES) + bias[t];
    }
}

extern "C" void kernel_launch(void* const* d_in, const int* in_sizes, int n_in,
                              void* d_out, int out_size, void* d_ws, size_t ws_size,
                              hipStream_t stream) {
    const int*   node_seq = (const int*)  d_in[0];
    const int*   eidx     = (const int*)  d_in[1];   // [2, E] flat
    const float* ew       = (const float*)d_in[2];
    const float* emb      = (const float*)d_in[3];
    const float* W        = (const float*)d_in[4];
    const float* bias     = (const float*)d_in[5];
    float*       out      = (float*)d_out;

    const int* row = eidx;
    const int* col = eidx + N_EDGES;

    char* wsb = (char*)d_ws;
    const size_t REC_BYTES = (size_t)NBKT * CAP * sizeof(uint2);  // ~19.3 MB
    uint2* recs    = (uint2*)wsb;
    int*   cursors = (int*)(wsb + REC_BYTES);
    uint2* disseq  = (uint2*)(wsb + REC_BYTES + 4096);
    float* gcoeff  = (float*)(disseq + N_NODES);
    float* coeff   = gcoeff + (size_t)NPART * VOCAB;

    void* args[] = {(void*)&node_seq, (void*)&row, (void*)&col, (void*)&ew,
                    (void*)&emb, (void*)&W, (void*)&bias, (void*)&out,
                    (void*)&cursors, (void*)&recs, (void*)&disseq,
                    (void*)&gcoeff, (void*)&coeff};
    hipError_t err = hipLaunchCooperativeKernel((const void*)k_fused,
                                                dim3(GRID), dim3(TPB),
                                                args, 0, stream);
    if (err != hipSuccess) {
        // fallback: proven multi-kernel path
        k_init<<<1, 256, 0, stream>>>(cursors);
        k_scatter<<<NSB, 256, 0, stream>>>(row, col, ew, cursors, recs);
        k_dis<<<NBKT, 256, 0, stream>>>(recs, cursors, node_seq, disseq);
        k_coeff<<<NBKT, 512, 0, stream>>>(recs, cursors, disseq, gcoeff);
        k_reduce<<<(VOCAB * 64 + 255) / 256, 256, 0, stream>>>(gcoeff, coeff, NBKT);
        k_final<<<1, 1024, 0, stream>>>(coeff, emb, W, bias, out);
    }
}

// Round 8
// 167.848 us; speedup vs baseline: 2.5199x; 2.5199x over previous
//
#include <hip/hip_runtime.h>

#define N_NODES 100000
#define N_EDGES 1600000
#define VOCAB   1000
#define EMB_DIM 64
#define OUT_DIM 32

#define BKT_BITS 9
#define BKT_SIZE 512
#define NBKT ((N_NODES + BKT_SIZE - 1) / BKT_SIZE)     // 196
#define CAP  10240                                     // per-bucket capacity (mean 8163, +23 sigma)
#define NSB  1000                                      // scatter blocks
#define CHUNK (N_EDGES / NSB)                          // 1600 exact
#define SPLIT 4
#define NPART (NBKT * SPLIT)                           // 784
#define NRF_BLOCKS 250                                 // reduce+final blocks (1000 waves)

__device__ __forceinline__ void fatomic_add(float* p, float v) {
    unsafeAtomicAdd(p, v);   // ds_add_f32 / global_atomic_add_f32, no return
}

// ---- K0: zero control block: cursors[NBKT], done, tvec[64] ----------------
__global__ void k_init(int* __restrict__ cursors, int* __restrict__ done,
                       float* __restrict__ tvec) {
    int i = threadIdx.x;
    if (i < NBKT) cursors[i] = 0;
    if (i == 0) *done = 0;
    if (i < 64) tvec[i] = 0.0f;
}

// ---- K1: LDS counting-sort scatter; coalesced segment writes --------------
// record: x = (row<<9) | local_col, y = w_bits ; keyed by col>>9
__global__ void __launch_bounds__(256) k_scatter(
        const int* __restrict__ row, const int* __restrict__ col,
        const float* __restrict__ w, int* __restrict__ cursors,
        uint2* __restrict__ recs) {
    __shared__ uint2 stage[CHUNK];                 // 12.8 KB
    __shared__ unsigned short seg[CHUNK];          //  3.2 KB
    __shared__ int cnt[NBKT], lofs[NBKT], gbase[NBKT];
    __shared__ int sc[256];
    const int tid = threadIdx.x;
    const int e0 = blockIdx.x * CHUNK;

    for (int i = tid; i < NBKT; i += 256) cnt[i] = 0;
    __syncthreads();
    for (int i = tid; i < CHUNK; i += 256)
        atomicAdd(&cnt[col[e0 + i] >> BKT_BITS], 1);
    __syncthreads();
    sc[tid] = (tid < NBKT) ? cnt[tid] : 0;
    __syncthreads();
    for (int d = 1; d < 256; d <<= 1) {
        int v = (tid >= d) ? sc[tid - d] : 0;
        __syncthreads();
        sc[tid] += v;
        __syncthreads();
    }
    if (tid < NBKT) {
        lofs[tid]  = sc[tid] - cnt[tid];                         // excl prefix
        gbase[tid] = tid * CAP + atomicAdd(&cursors[tid], cnt[tid]);
        cnt[tid]   = 0;
    }
    __syncthreads();
    for (int i = tid; i < CHUNK; i += 256) {
        int c = col[e0 + i];                                     // L2-warm reread
        int r = row[e0 + i];
        int b = c >> BKT_BITS;
        int p = lofs[b] + atomicAdd(&cnt[b], 1);
        stage[p] = make_uint2(((unsigned)r << BKT_BITS) | (unsigned)(c & (BKT_SIZE - 1)),
                              __float_as_uint(w[e0 + i]));
        seg[p] = (unsigned short)b;
    }
    __syncthreads();
    for (int i = tid; i < CHUNK; i += 256) {
        int b = seg[i];
        recs[gbase[b] + (i - lofs[b])] = stage[i];
    }
}

// ---- K2: per bucket: deg accumulate -> disseq = {rsqrt(1+deg), seq} -------
__global__ void __launch_bounds__(512) k_dis(
        const uint2* __restrict__ recs, const int* __restrict__ cursors,
        const int* __restrict__ node_seq, uint2* __restrict__ disseq) {
    __shared__ float acc[BKT_SIZE];
    const int b = blockIdx.x;
    if (threadIdx.x < BKT_SIZE) acc[threadIdx.x] = 0.0f;
    __syncthreads();
    const int base = b * CAP;
    const int cnt = cursors[b];
    for (int i = threadIdx.x; i < cnt; i += 512) {
        uint2 r = recs[base + i];
        fatomic_add(&acc[r.x & (BKT_SIZE - 1)], __uint_as_float(r.y));
    }
    __syncthreads();
    const int n0 = b << BKT_BITS;
    if (threadIdx.x < BKT_SIZE) {
        int n = n0 + threadIdx.x;
        if (n < N_NODES)
            disseq[n] = make_uint2(__float_as_uint(__frsqrt_rn(1.0f + acc[threadIdx.x])),
                                   (unsigned)node_seq[n]);
    }
}

// ---- K3: per (bucket, quarter): vocab histogram; 1 8B gather per edge -----
__global__ void __launch_bounds__(512) k_coeff(
        const uint2* __restrict__ recs, const int* __restrict__ cursors,
        const uint2* __restrict__ disseq, float* __restrict__ gcoeff) {
    __shared__ float dloc[BKT_SIZE];
    __shared__ float lc[VOCAB];
    const int b = blockIdx.x >> 2, s = blockIdx.x & 3;
    const int n0 = b << BKT_BITS;
    for (int i = threadIdx.x; i < VOCAB; i += 512) lc[i] = 0.0f;
    if (threadIdx.x < BKT_SIZE) {
        int n = n0 + threadIdx.x;
        dloc[threadIdx.x] = (n < N_NODES) ? __uint_as_float(disseq[n].x) : 0.0f;
    }
    __syncthreads();
    const int base = b * CAP;
    const int cnt = cursors[b];
    const int lo = (cnt * s) >> 2;
    const int hi = (cnt * (s + 1)) >> 2;
    for (int i = lo + threadIdx.x; i < hi; i += 512) {
        uint2 rec = recs[base + i];
        int lcol = rec.x & (BKT_SIZE - 1);
        int r    = rec.x >> BKT_BITS;
        uint2 ds = disseq[r];                                    // 8B L2 gather
        fatomic_add(&lc[ds.y],
            __uint_as_float(ds.x) * __uint_as_float(rec.y) * dloc[lcol]);
    }
    if (s == 0 && threadIdx.x < BKT_SIZE) {                      // self loops
        int n = n0 + threadIdx.x;
        if (n < N_NODES) {
            uint2 ds = disseq[n];
            float d = __uint_as_float(ds.x);
            fatomic_add(&lc[ds.y], d * d);
        }
    }
    __syncthreads();
    for (int i = threadIdx.x; i < VOCAB; i += 512)
        gcoeff[blockIdx.x * VOCAB + i] = lc[i];
}

// ---- K4: reduce partials -> coeff[v]; fold into tvec[k]; last block -> out
__global__ void __launch_bounds__(256) k_reduce_final(
        const float* __restrict__ gcoeff, const float* __restrict__ emb,
        const float* __restrict__ W, const float* __restrict__ bias,
        float* __restrict__ tvec, int* __restrict__ done,
        float* __restrict__ out) {
    __shared__ int lastflag;
    const int tid = threadIdx.x;
    const int v = (blockIdx.x * 256 + tid) >> 6;                 // vocab slot
    const int l = tid & 63;
    if (v < VOCAB) {
        float s = 0.0f;
        for (int p = l; p < NPART; p += 64) s += gcoeff[p * VOCAB + v];
        for (int off = 32; off > 0; off >>= 1) s += __shfl_down(s, off, 64);
        float cv = __shfl(s, 0, 64);                             // broadcast coeff[v]
        fatomic_add(&tvec[l], cv * emb[v * EMB_DIM + l]);        // t[k] += coeff*emb
    }
    __syncthreads();
    if (tid == 0) {
        __threadfence();                                         // release tvec adds
        int t = atomicAdd(done, 1);
        lastflag = (t == NRF_BLOCKS - 1) ? 1 : 0;
    }
    __syncthreads();
    if (lastflag) {
        __threadfence();                                         // acquire
        __shared__ float tk[EMB_DIM];
        if (tid < EMB_DIM) tk[tid] = ((volatile float*)tvec)[tid];
        __syncthreads();
        if (tid < OUT_DIM) {
            float s = 0.0f;
            #pragma unroll
            for (int k = 0; k < EMB_DIM; ++k) s += tk[k] * W[k * OUT_DIM + tid];
            out[tid] = s * (1.0f / (float)N_NODES) + bias[tid];
        }
    }
}

extern "C" void kernel_launch(void* const* d_in, const int* in_sizes, int n_in,
                              void* d_out, int out_size, void* d_ws, size_t ws_size,
                              hipStream_t stream) {
    const int*   node_seq = (const int*)  d_in[0];
    const int*   eidx     = (const int*)  d_in[1];   // [2, E] flat
    const float* ew       = (const float*)d_in[2];
    const float* emb      = (const float*)d_in[3];
    const float* W        = (const float*)d_in[4];
    const float* bias     = (const float*)d_in[5];
    float*       out      = (float*)d_out;

    const int* row = eidx;
    const int* col = eidx + N_EDGES;

    char* wsb = (char*)d_ws;
    const size_t REC_BYTES = (size_t)NBKT * CAP * sizeof(uint2); // 16.05 MB
    uint2* recs    = (uint2*)wsb;
    int*   cursors = (int*)(wsb + REC_BYTES);                    // NBKT ints
    int*   done    = cursors + NBKT;
    float* tvec    = (float*)(done + 1);                         // 64 floats
    uint2* disseq  = (uint2*)(wsb + REC_BYTES + 4096);
    float* gcoeff  = (float*)(disseq + N_NODES);                 // NPART*VOCAB

    k_init<<<1, 512, 0, stream>>>(cursors, done, tvec);
    k_scatter<<<NSB, 256, 0, stream>>>(row, col, ew, cursors, recs);
    k_dis<<<NBKT, 512, 0, stream>>>(recs, cursors, node_seq, disseq);
    k_coeff<<<NPART, 512, 0, stream>>>(recs, cursors, disseq, gcoeff);
    k_reduce_final<<<NRF_BLOCKS, 256, 0, stream>>>(gcoeff, emb, W, bias,
                                                   tvec, done, out);
}

// Round 9
// 158.253 us; speedup vs baseline: 2.6727x; 1.0606x over previous
//
#include <hip/hip_runtime.h>

#define N_NODES 100000
#define N_EDGES 1600000
#define VOCAB   1000
#define EMB_DIM 64
#define OUT_DIM 32

#define BKT_BITS 9
#define BKT_SIZE 512
#define NBKT ((N_NODES + BKT_SIZE - 1) / BKT_SIZE)     // 196
#define CAP  10240                                     // per-bucket capacity (mean 8163, +23 sigma)
#define NSB  512                                       // scatter blocks (r4-proven)
#define CHUNK (N_EDGES / NSB)                          // 3125 exact
#define SPLIT 4
#define NPART (NBKT * SPLIT)                           // 784
#define NRF_BLOCKS 250                                 // reduce+final blocks (1000 waves)

__device__ __forceinline__ void fatomic_add(float* p, float v) {
    unsafeAtomicAdd(p, v);   // ds_add_f32 / global_atomic_add_f32, no return
}

// ---- K0: zero cursors + ticket --------------------------------------------
__global__ void k_init(int* __restrict__ cursors, int* __restrict__ done) {
    int i = threadIdx.x;
    if (i < NBKT) cursors[i] = 0;
    if (i == NBKT) *done = 0;
}

// ---- K1: LDS counting-sort scatter; coalesced segment writes --------------
// record: x = (row<<9) | local_col, y = w_bits ; keyed by col>>9
__global__ void __launch_bounds__(256) k_scatter(
        const int* __restrict__ row, const int* __restrict__ col,
        const float* __restrict__ w, int* __restrict__ cursors,
        uint2* __restrict__ recs) {
    __shared__ uint2 stage[CHUNK];                 // 25.0 KB
    __shared__ unsigned char seg[CHUNK];           //  3.1 KB
    __shared__ int cnt[NBKT], lofs[NBKT], gbase[NBKT];
    __shared__ int sc[256];
    const int tid = threadIdx.x;
    const int e0 = blockIdx.x * CHUNK;

    for (int i = tid; i < NBKT; i += 256) cnt[i] = 0;
    __syncthreads();
    for (int i = tid; i < CHUNK; i += 256)
        atomicAdd(&cnt[col[e0 + i] >> BKT_BITS], 1);
    __syncthreads();
    sc[tid] = (tid < NBKT) ? cnt[tid] : 0;
    __syncthreads();
    for (int d = 1; d < 256; d <<= 1) {
        int v = (tid >= d) ? sc[tid - d] : 0;
        __syncthreads();
        sc[tid] += v;
        __syncthreads();
    }
    if (tid < NBKT) {
        lofs[tid]  = sc[tid] - cnt[tid];                          // excl prefix
        gbase[tid] = tid * CAP + atomicAdd(&cursors[tid], cnt[tid]);
        cnt[tid]   = 0;
    }
    __syncthreads();
    for (int i = tid; i < CHUNK; i += 256) {
        int c = col[e0 + i];                                      // L2-warm reread
        int r = row[e0 + i];
        int b = c >> BKT_BITS;
        int p = lofs[b] + atomicAdd(&cnt[b], 1);
        stage[p] = make_uint2(((unsigned)r << BKT_BITS) | (unsigned)(c & (BKT_SIZE - 1)),
                              __float_as_uint(w[e0 + i]));
        seg[p] = (unsigned char)b;
    }
    __syncthreads();
    // consecutive i -> consecutive dst within each ~16-record segment
    for (int i = tid; i < CHUNK; i += 256) {
        int b = seg[i];
        recs[gbase[b] + (i - lofs[b])] = stage[i];
    }
}

// ---- K2: per bucket: deg accumulate -> disseq = {rsqrt(1+deg), seq} -------
__global__ void __launch_bounds__(512) k_dis(
        const uint2* __restrict__ recs, const int* __restrict__ cursors,
        const int* __restrict__ node_seq, uint2* __restrict__ disseq) {
    __shared__ float acc[BKT_SIZE];
    const int b = blockIdx.x;
    if (threadIdx.x < BKT_SIZE) acc[threadIdx.x] = 0.0f;
    __syncthreads();
    const int base = b * CAP;
    const int cnt = cursors[b];
    for (int i = threadIdx.x; i < cnt; i += 512) {
        uint2 r = recs[base + i];
        fatomic_add(&acc[r.x & (BKT_SIZE - 1)], __uint_as_float(r.y));
    }
    __syncthreads();
    const int n0 = b << BKT_BITS;
    if (threadIdx.x < BKT_SIZE) {
        int n = n0 + threadIdx.x;
        if (n < N_NODES)
            disseq[n] = make_uint2(__float_as_uint(__frsqrt_rn(1.0f + acc[threadIdx.x])),
                                   (unsigned)node_seq[n]);
    }
}

// ---- K3: per (bucket, quarter): vocab histogram; 1 8B gather per edge -----
__global__ void __launch_bounds__(512) k_coeff(
        const uint2* __restrict__ recs, const int* __restrict__ cursors,
        const uint2* __restrict__ disseq, float* __restrict__ gcoeff) {
    __shared__ float dloc[BKT_SIZE];
    __shared__ float lc[VOCAB];
    const int b = blockIdx.x >> 2, s = blockIdx.x & 3;
    const int n0 = b << BKT_BITS;
    for (int i = threadIdx.x; i < VOCAB; i += 512) lc[i] = 0.0f;
    if (threadIdx.x < BKT_SIZE) {
        int n = n0 + threadIdx.x;
        dloc[threadIdx.x] = (n < N_NODES) ? __uint_as_float(disseq[n].x) : 0.0f;
    }
    __syncthreads();
    const int base = b * CAP;
    const int cnt = cursors[b];
    const int lo = (cnt * s) >> 2;
    const int hi = (cnt * (s + 1)) >> 2;
    for (int i = lo + threadIdx.x; i < hi; i += 512) {
        uint2 rec = recs[base + i];
        int lcol = rec.x & (BKT_SIZE - 1);
        int r    = rec.x >> BKT_BITS;
        uint2 ds = disseq[r];                                     // 8B L2 gather
        fatomic_add(&lc[ds.y],
            __uint_as_float(ds.x) * __uint_as_float(rec.y) * dloc[lcol]);
    }
    if (s == 0 && threadIdx.x < BKT_SIZE) {                       // self loops
        int n = n0 + threadIdx.x;
        if (n < N_NODES) {
            uint2 ds = disseq[n];
            float d = __uint_as_float(ds.x);
            fatomic_add(&lc[ds.y], d * d);
        }
    }
    __syncthreads();
    for (int i = threadIdx.x; i < VOCAB; i += 512)
        gcoeff[blockIdx.x * VOCAB + i] = lc[i];
}

// ---- K4: reduce partials -> coeff; fold into per-block tpart; last -> out -
__global__ void __launch_bounds__(256) k_reduce_final(
        const float* __restrict__ gcoeff, const float* __restrict__ emb,
        const float* __restrict__ W, const float* __restrict__ bias,
        float* __restrict__ tpart, int* __restrict__ done,
        float* __restrict__ out) {
    __shared__ float tk[EMB_DIM];
    __shared__ int lastflag;
    const int tid = threadIdx.x;
    const int l = tid & 63;
    if (tid < EMB_DIM) tk[tid] = 0.0f;
    __syncthreads();
    {   // this block covers 4 vocab slots (one per wave)
        const int v = (blockIdx.x * 256 + tid) >> 6;              // 0..999
        float s = 0.0f;
        for (int p = l; p < NPART; p += 64) s += gcoeff[p * VOCAB + v];
        for (int off = 32; off > 0; off >>= 1) s += __shfl_down(s, off, 64);
        float cv = __shfl(s, 0, 64);                              // coeff[v]
        fatomic_add(&tk[l], cv * emb[v * EMB_DIM + l]);           // LDS, 4-way
    }
    __syncthreads();
    if (tid < EMB_DIM) tpart[blockIdx.x * EMB_DIM + tid] = tk[tid];
    __syncthreads();
    if (tid == 0) {
        __threadfence();                                          // release tpart row
        lastflag = (atomicAdd(done, 1) == NRF_BLOCKS - 1) ? 1 : 0;
    }
    __syncthreads();
    if (lastflag) {
        __threadfence();                                          // acquire
        __shared__ float tk2[4][EMB_DIM];
        const int g = tid >> 6;                                   // 0..3
        float s = 0.0f;
        for (int p = g; p < NRF_BLOCKS; p += 4)
            s += ((volatile float*)tpart)[p * EMB_DIM + l];
        tk2[g][l] = s;
        __syncthreads();
        if (tid < EMB_DIM)
            tk[tid] = tk2[0][tid] + tk2[1][tid] + tk2[2][tid] + tk2[3][tid];
        __syncthreads();
        if (tid < OUT_DIM) {
            float s2 = 0.0f;
            #pragma unroll
            for (int k = 0; k < EMB_DIM; ++k) s2 += tk[k] * W[k * OUT_DIM + tid];
            out[tid] = s2 * (1.0f / (float)N_NODES) + bias[tid];
        }
    }
}

extern "C" void kernel_launch(void* const* d_in, const int* in_sizes, int n_in,
                              void* d_out, int out_size, void* d_ws, size_t ws_size,
                              hipStream_t stream) {
    const int*   node_seq = (const int*)  d_in[0];
    const int*   eidx     = (const int*)  d_in[1];   // [2, E] flat
    const float* ew       = (const float*)d_in[2];
    const float* emb      = (const float*)d_in[3];
    const float* W        = (const float*)d_in[4];
    const float* bias     = (const float*)d_in[5];
    float*       out      = (float*)d_out;

    const int* row = eidx;
    const int* col = eidx + N_EDGES;

    char* wsb = (char*)d_ws;
    const size_t REC_BYTES = (size_t)NBKT * CAP * sizeof(uint2); // 16.05 MB
    uint2* recs    = (uint2*)wsb;
    int*   cursors = (int*)(wsb + REC_BYTES);                    // NBKT ints
    int*   done    = cursors + NBKT;
    uint2* disseq  = (uint2*)(wsb + REC_BYTES + 4096);
    float* gcoeff  = (float*)(disseq + N_NODES);                 // NPART*VOCAB
    float* tpart   = gcoeff + (size_t)NPART * VOCAB;             // NRF_BLOCKS*64

    k_init<<<1, 256, 0, stream>>>(cursors, done);
    k_scatter<<<NSB, 256, 0, stream>>>(row, col, ew, cursors, recs);
    k_dis<<<NBKT, 512, 0, stream>>>(recs, cursors, node_seq, disseq);
    k_coeff<<<NPART, 512, 0, stream>>>(recs, cursors, disseq, gcoeff);
    k_reduce_final<<<NRF_BLOCKS, 256, 0, stream>>>(gcoeff, emb, W, bias,
                                                   tpart, done, out);
}